// Round 15
// baseline (73.237 us; speedup 1.0000x reference)
//
#include <hip/hip_runtime.h>
#include <math.h>

typedef _Float16 half8 __attribute__((ext_vector_type(8)));
typedef float    f32x4 __attribute__((ext_vector_type(4)));

#define TOKENS  32768
#define HIDDEN  2048
#define EXPERTS 64
#define TOPK    8
#define TB      128                // tokens per block
#define KHALF   1024               // k per K-half (in-block K-split by 2)
#define BKW     64                 // k per staged W window
#define NWIN    (KHALF / BKW)      // 16
#define LDH     72                 // W LDS row stride in halves (144 B)
#define REGH    (2 * 64 * LDH)     // halves per (h,buf) region: hi[64][72] | lo[64][72]

// ---------------------------------------------------------------------------
// Kernel 1: split W fp32 -> (Whi, Wlo) fp16, row-major [64][2048] in d_ws.
// ---------------------------------------------------------------------------
__global__ void wsplit(const float* __restrict__ W,
                       _Float16* __restrict__ whi, _Float16* __restrict__ wlo) {
    int i = blockIdx.x * 256 + threadIdx.x;     // 0..131071
    float w = W[i];
    _Float16 h = (_Float16)w;
    whi[i] = h;
    wlo[i] = (_Float16)(w - (float)h);
}

// ---------------------------------------------------------------------------
// Kernel 2: MFMA router, fp16x3 split (hi*hi + hi*lo + lo*hi, fp32 acc).
// r14: 512 thr / 128 tokens / in-block K-split. Wave (h,q) = K-half h x
// token-quarter q: 32 tok x 64 exp x 1024 k. A: global->reg->cvt->frag
// DIRECTLY (no A-LDS, cvt exactly once per element); 2-window static queue.
// W: LDS, per-half double-buffer (r12's verified pattern). Per-CU LDS traffic
// drops ~3x vs r8 (B-reads 2048 b128 + W-writes 512 ~= 12.6us vs 37.5us).
// Epilogue: half1 dumps partials, half0 adds + bias, top-8 per token.
// Grid 256 = 1 block/CU (8 waves, 2/SIMD).
// ---------------------------------------------------------------------------
__global__ __launch_bounds__(512, 1)
void router_ks(const float* __restrict__ A,
               const _Float16* __restrict__ Wh,
               const _Float16* __restrict__ Wl,
               const float* __restrict__ bias,
               float* __restrict__ out) {
    __shared__ __align__(16) _Float16 hsm[4 * REGH];   // 73728 B: (h,buf) regions
    const int tid = threadIdx.x;
    const int wv  = tid >> 6;
    const int l   = tid & 63;
    const int g   = blockIdx.x;
    const int h   = wv >> 2;           // K-half
    const int q   = wv & 3;            // token quarter (32 tokens)

    // A direct-load bases: two frag rows (q*32 + (l&15)) and (+16)
    const float* pa = A + ((size_t)(g * TB + q * 32 + (l & 15))) * HIDDEN
                        + h * KHALF + ((l >> 4) << 3);
    const float* pb = pa + (size_t)16 * HIDDEN;

    // W staging map (per half, 256 threads): expert row er, chunks wc*8, wc*8+32
    const int er = (tid & 255) >> 2;
    const int wc = tid & 3;
    const _Float16* WhB = Wh + (size_t)er * HIDDEN + h * KHALF;
    const _Float16* WlB = Wl + (size_t)er * HIDDEN + h * KHALF;

    _Float16* reg0 = hsm + (h * 2 + 0) * REGH;   // this half's buffers
    _Float16* reg1 = hsm + (h * 2 + 1) * REGH;

    f32x4 acc[2][4];
    #pragma unroll
    for (int rb = 0; rb < 2; ++rb)
        #pragma unroll
        for (int n = 0; n < 4; ++n) acc[rb][n] = (f32x4){0.f, 0.f, 0.f, 0.f};

    // A queue: two static window-sets, 8 float4 each ([rb][ks][chunk])
    float4 qA0, qA1, qA2, qA3, qA4, qA5, qA6, qA7;
    float4 qB0, qB1, qB2, qB3, qB4, qB5, qB6, qB7;
    half8 swh0, swh1, swl0, swl1;      // W staging regs

    #define LOADA(S, win) do {                                               \
        const float* pa_ = pa + (win) * BKW;                                 \
        const float* pb_ = pb + (win) * BKW;                                 \
        q##S##0 = *(const float4*)(pa_);      q##S##1 = *(const float4*)(pa_ + 4);  \
        q##S##2 = *(const float4*)(pa_ + 32); q##S##3 = *(const float4*)(pa_ + 36); \
        q##S##4 = *(const float4*)(pb_);      q##S##5 = *(const float4*)(pb_ + 4);  \
        q##S##6 = *(const float4*)(pb_ + 32); q##S##7 = *(const float4*)(pb_ + 36); \
    } while (0)

    #define LOADW(win) do {                                                  \
        swh0 = *(const half8*)(WhB + (win) * BKW + wc * 8);                  \
        swh1 = *(const half8*)(WhB + (win) * BKW + wc * 8 + 32);             \
        swl0 = *(const half8*)(WlB + (win) * BKW + wc * 8);                  \
        swl1 = *(const half8*)(WlB + (win) * BKW + wc * 8 + 32);             \
    } while (0)

    #define STOREW(R) do {                                                   \
        *(half8*)(&(R)[er * LDH + wc * 8])                 = swh0;           \
        *(half8*)(&(R)[er * LDH + wc * 8 + 32])            = swh1;           \
        *(half8*)(&(R)[64 * LDH + er * LDH + wc * 8])      = swl0;           \
        *(half8*)(&(R)[64 * LDH + er * LDH + wc * 8 + 32]) = swl1;           \
    } while (0)

    #define CVT8(HI, LO, V0, V1) do {                                        \
        float f_[8] = {(V0).x, (V0).y, (V0).z, (V0).w,                       \
                       (V1).x, (V1).y, (V1).z, (V1).w};                      \
        _Pragma("unroll")                                                    \
        for (int j_ = 0; j_ < 8; ++j_) {                                     \
            _Float16 h_ = (_Float16)f_[j_];                                  \
            (HI)[j_] = h_;                                                   \
            (LO)[j_] = (_Float16)(f_[j_] - (float)h_);                       \
        }                                                                    \
    } while (0)

    // one k-slice (32 k) for one row-block: cvt A pair + 4 expert tiles
    #define KSLICE(R, RB, KO, V0, V1) do {                                   \
        half8 ahi_, alo_;                                                    \
        CVT8(ahi_, alo_, V0, V1);                                            \
        _Pragma("unroll")                                                    \
        for (int n = 0; n < 4; ++n) {                                        \
            half8 bh = *(const half8*)(&(R)[(n * 16 + (l & 15)) * LDH + (KO)]); \
            half8 bl = *(const half8*)(&(R)[64 * LDH + (n * 16 + (l & 15)) * LDH + (KO)]); \
            acc[RB][n] = __builtin_amdgcn_mfma_f32_16x16x32_f16(ahi_, bh, acc[RB][n], 0, 0, 0); \
            acc[RB][n] = __builtin_amdgcn_mfma_f32_16x16x32_f16(ahi_, bl, acc[RB][n], 0, 0, 0); \
            acc[RB][n] = __builtin_amdgcn_mfma_f32_16x16x32_f16(alo_, bh, acc[RB][n], 0, 0, 0); \
        }                                                                    \
    } while (0)

    #define COMPUTE(R, S) do {                                               \
        const int ko0_ = (l >> 4) << 3;                                      \
        KSLICE(R, 0, ko0_,      q##S##0, q##S##1);                           \
        KSLICE(R, 1, ko0_,      q##S##4, q##S##5);                           \
        KSLICE(R, 0, ko0_ + 32, q##S##2, q##S##3);                           \
        KSLICE(R, 1, ko0_ + 32, q##S##6, q##S##7);                           \
    } while (0)

    // ---- prologue ----
    LOADW(0);
    STOREW(reg0);
    LOADA(A, 0);
    __syncthreads();

    // ---- main loop: 1 barrier per window, 2-window A queue, W dbuf ----
    #pragma unroll 1
    for (int s = 0; s < NWIN; s += 2) {
        LOADW(s + 1);                            // s+1 <= 15 always
        LOADA(B, s + 1);
        COMPUTE(reg0, A);                        // window s
        STOREW(reg1);
        __syncthreads();

        if (s + 2 < NWIN) {
            LOADW(s + 2);
            LOADA(A, s + 2);
        }
        COMPUTE(reg1, B);                        // window s+1
        if (s + 2 < NWIN) STOREW(reg0);
        __syncthreads();
    }
    #undef LOADA
    #undef LOADW
    #undef STOREW
    #undef CVT8
    #undef KSLICE
    #undef COMPUTE

    // ---- epilogue: cross-half reduce + bias, top-8, scatter ----
    float* lg = (float*)hsm;                   // [128 tok][68]
    float* sc = (float*)hsm + TB * 68;         // [128 tok][65]

    // D layout (verified r8): within tile (rb,n): token = q*32+rb*16+(l>>4)*4+j,
    // expert col = n*16+(l&15)
    if (h == 1) {
        #pragma unroll
        for (int rb = 0; rb < 2; ++rb)
            #pragma unroll
            for (int n = 0; n < 4; ++n)
                #pragma unroll
                for (int j = 0; j < 4; ++j)
                    lg[(q * 32 + rb * 16 + (l >> 4) * 4 + j) * 68 + n * 16 + (l & 15)]
                        = acc[rb][n][j];
    }
    __syncthreads();
    if (h == 0) {
        #pragma unroll
        for (int rb = 0; rb < 2; ++rb)
            #pragma unroll
            for (int n = 0; n < 4; ++n) {
                float b = bias[n * 16 + (l & 15)];
                #pragma unroll
                for (int j = 0; j < 4; ++j) {
                    int idx = (q * 32 + rb * 16 + (l >> 4) * 4 + j) * 68 + n * 16 + (l & 15);
                    lg[idx] = lg[idx] + acc[rb][n][j] + b;
                }
            }
    }
    for (int i = tid; i < TB * 65; i += 512) sc[i] = 0.f;
    __syncthreads();

    if (tid < TB) {
        const int t = tid;
        float v[64];
        #pragma unroll
        for (int e = 0; e < 64; ++e) v[e] = lg[t * 68 + e];

        float tvals[TOPK]; int tix[TOPK]; float probs[TOPK];
        unsigned long long chosen = 0ull;
        #pragma unroll
        for (int j = 0; j < TOPK; ++j) {
            float best = -INFINITY; int bi = 0;
            #pragma unroll
            for (int e = 0; e < 64; ++e) {
                bool ok = ((chosen >> e) & 1ull) == 0ull;
                if (ok && v[e] > best) { best = v[e]; bi = e; }  // strict >: lowest idx on tie
            }
            chosen |= (1ull << bi);
            tvals[j] = best; tix[j] = bi;
        }
        float m = tvals[0];
        float ssum = 0.f;
        #pragma unroll
        for (int j = 0; j < TOPK; ++j) { probs[j] = __expf(tvals[j] - m); ssum += probs[j]; }
        float inv = 1.f / ssum;
        #pragma unroll
        for (int j = 0; j < TOPK; ++j) probs[j] *= inv;

        #pragma unroll
        for (int j = 0; j < TOPK; ++j) sc[t * 65 + tix[j]] = probs[j];

        float* oidx = out + (size_t)TOKENS * EXPERTS;
        const int token = g * TB + t;
        #pragma unroll
        for (int j = 0; j < TOPK; ++j) oidx[(size_t)token * TOPK + j] = (float)tix[j];
    }
    __syncthreads();

    // ---- coalesced score write: 128 tokens x 64 experts = 2048 float4 ----
    float* oscore = out + (size_t)g * (TB * 64);
    #pragma unroll
    for (int p = 0; p < 4; ++p) {
        int fi  = tid + 512 * p;               // float4 index 0..2047
        int tok = fi >> 4;
        int es  = (fi & 15) * 4;
        float4 vv;
        vv.x = sc[tok * 65 + es + 0];
        vv.y = sc[tok * 65 + es + 1];
        vv.z = sc[tok * 65 + es + 2];
        vv.w = sc[tok * 65 + es + 3];
        *(float4*)(oscore + (size_t)fi * 4) = vv;
    }
}

extern "C" void kernel_launch(void* const* d_in, const int* in_sizes, int n_in,
                              void* d_out, int out_size, void* d_ws, size_t ws_size,
                              hipStream_t stream) {
    const float* A    = (const float*)d_in[0];   // [32768, 2048] fp32
    const float* W    = (const float*)d_in[1];   // [64, 2048] fp32
    const float* bias = (const float*)d_in[2];   // [64] fp32
    float* out = (float*)d_out;                  // scores (32768*64) ++ idx (32768*8)

    _Float16* whi = (_Float16*)d_ws;             // 256 KB
    _Float16* wlo = whi + EXPERTS * HIDDEN;      // 256 KB

    wsplit<<<512, 256, 0, stream>>>(W, whi, wlo);
    router_ks<<<TOKENS / TB, 512, 0, stream>>>(A, whi, wlo, bias, out);
}

// Round 16
// 61.215 us; speedup vs baseline: 1.1964x; 1.1964x over previous
//
#include <hip/hip_runtime.h>
#include <math.h>

typedef _Float16 half8 __attribute__((ext_vector_type(8)));
typedef _Float16 half4 __attribute__((ext_vector_type(4)));
typedef float    f32x4 __attribute__((ext_vector_type(4)));

#define TOKENS  32768
#define HIDDEN  2048
#define EXPERTS 64
#define TOPK    8
#define BKW     64               // k per staged window
#define NWIN    (HIDDEN / BKW)   // 32
#define LDH     72               // LDS row stride in halves (144 B: 16B-aligned)

// ---------------------------------------------------------------------------
// Single fused kernel == r8 (best, 64.8us) with the W fp32->hi/lo split done
// INLINE during staging (wsplit kernel deleted -> no second dispatch, no
// stream serialization, no d_ws round-trip). Everything else identical to r8:
// Block = 256 thr (4 waves) owns 64 tokens x 64 experts x full K.
// Wave w: token slab [w*16,+16), all 4 expert tiles (acc 4 x f32x4).
// Per 64-k window: stage A (fp32->hi/lo) and W (fp32->hi/lo inline) into LDS
// (row-major, stride 144B), single-buffered, 2 barriers/window; next-window
// global loads fly during compute. Frags: A[t][k..k+7] / W[e][k..k+7]
// 16B-contiguous -> ds_read_b128, no transpose anywhere.
// Epilogue: logits(+bias) -> LDS, per-token top-8 + softmax + scatter.
// ---------------------------------------------------------------------------
__global__ __launch_bounds__(256, 1)
void router_mfma(const float* __restrict__ A,
                 const float* __restrict__ W,
                 const float* __restrict__ bias,
                 float* __restrict__ out) {
    __shared__ __align__(16) _Float16 hsm[4 * 64 * LDH];   // Ahi|Alo|Whi|Wlo = 36864 B
    _Float16* Ahs = hsm;
    _Float16* Als = hsm + 64 * LDH;
    _Float16* Whs = hsm + 2 * 64 * LDH;
    _Float16* Wls = hsm + 3 * 64 * LDH;

    const int tid = threadIdx.x;
    const int w   = tid >> 6;          // wave = 16-token slab
    const int l   = tid & 63;
    const int g   = blockIdx.x;

    // A staging map: 4 rounds x (16 rows x 16 float4-chunks) -- coalesced
    const int s_tok = tid >> 4;        // 0..15
    const int s_c   = tid & 15;        // k-chunk: floats s_c*4..s_c*4+3
    // W staging map: thread -> expert row, two 8-float chunks (wc*8, wc*8+32)
    const int we = tid >> 2;           // 0..63
    const int wc = tid & 3;

    const float* Abase = A + (size_t)g * 64 * HIDDEN;
    const float* WBase = W + (size_t)we * HIDDEN;

    f32x4 acc[4];
    #pragma unroll
    for (int n = 0; n < 4; ++n) acc[n] = (f32x4){0.f, 0.f, 0.f, 0.f};

    float4 ar0, ar1, ar2, ar3;         // A staging regs (4 rows)
    float4 wr0, wr1, wr2, wr3;         // W staging regs (fp32: 2 chunks x 2 float4)

    #define LOADA(win) do {                                                  \
        const float* p_ = Abase + (size_t)(win) * BKW + s_c * 4;             \
        ar0 = *(const float4*)(p_ + (size_t)(s_tok     ) * HIDDEN);          \
        ar1 = *(const float4*)(p_ + (size_t)(s_tok + 16) * HIDDEN);          \
        ar2 = *(const float4*)(p_ + (size_t)(s_tok + 32) * HIDDEN);          \
        ar3 = *(const float4*)(p_ + (size_t)(s_tok + 48) * HIDDEN);          \
    } while (0)

    #define LOADW(win) do {                                                  \
        const float* q_ = WBase + (size_t)(win) * BKW + wc * 8;              \
        wr0 = *(const float4*)(q_);                                          \
        wr1 = *(const float4*)(q_ + 4);                                      \
        wr2 = *(const float4*)(q_ + 32);                                     \
        wr3 = *(const float4*)(q_ + 36);                                     \
    } while (0)

    // split one float4 into hi/lo half4 and store to (HS,LS) at half-offset OFF
    #define SPLIT4(HS, LS, v, OFF) do {                                      \
        _Float16 h0_ = (_Float16)(v).x, h1_ = (_Float16)(v).y;               \
        _Float16 h2_ = (_Float16)(v).z, h3_ = (_Float16)(v).w;               \
        half4 hh_ = {h0_, h1_, h2_, h3_};                                    \
        half4 ll_ = {(_Float16)((v).x - (float)h0_),                         \
                     (_Float16)((v).y - (float)h1_),                         \
                     (_Float16)((v).z - (float)h2_),                         \
                     (_Float16)((v).w - (float)h3_)};                        \
        *(half4*)(&(HS)[(OFF)]) = hh_;                                       \
        *(half4*)(&(LS)[(OFF)]) = ll_;                                       \
    } while (0)

    #define STAGE() do {                                                     \
        SPLIT4(Ahs, Als, ar0, (s_tok     ) * LDH + s_c * 4);                 \
        SPLIT4(Ahs, Als, ar1, (s_tok + 16) * LDH + s_c * 4);                 \
        SPLIT4(Ahs, Als, ar2, (s_tok + 32) * LDH + s_c * 4);                 \
        SPLIT4(Ahs, Als, ar3, (s_tok + 48) * LDH + s_c * 4);                 \
        SPLIT4(Whs, Wls, wr0, we * LDH + wc * 8);                            \
        SPLIT4(Whs, Wls, wr1, we * LDH + wc * 8 + 4);                        \
        SPLIT4(Whs, Wls, wr2, we * LDH + wc * 8 + 32);                       \
        SPLIT4(Whs, Wls, wr3, we * LDH + wc * 8 + 36);                       \
    } while (0)

    LOADA(0);
    LOADW(0);

    #pragma unroll 1
    for (int win = 0; win < NWIN; ++win) {
        __syncthreads();                       // previous window fully consumed
        STAGE();
        __syncthreads();                       // window published

        if (win + 1 < NWIN) {                  // next-window loads fly during MFMA
            LOADA(win + 1);
            LOADW(win + 1);
        }

        #pragma unroll
        for (int ks = 0; ks < 2; ++ks) {
            const int ko = ks * 32 + (l >> 4) * 8;
            half8 ahi = *(const half8*)(&Ahs[(w * 16 + (l & 15)) * LDH + ko]);
            half8 alo = *(const half8*)(&Als[(w * 16 + (l & 15)) * LDH + ko]);
            #pragma unroll
            for (int n = 0; n < 4; ++n) {
                half8 bh = *(const half8*)(&Whs[(n * 16 + (l & 15)) * LDH + ko]);
                half8 bl = *(const half8*)(&Wls[(n * 16 + (l & 15)) * LDH + ko]);
                acc[n] = __builtin_amdgcn_mfma_f32_16x16x32_f16(ahi, bh, acc[n], 0, 0, 0);
                acc[n] = __builtin_amdgcn_mfma_f32_16x16x32_f16(ahi, bl, acc[n], 0, 0, 0);
                acc[n] = __builtin_amdgcn_mfma_f32_16x16x32_f16(alo, bh, acc[n], 0, 0, 0);
            }
        }
    }
    #undef LOADA
    #undef LOADW
    #undef SPLIT4
    #undef STAGE

    // ---- epilogue: logits (+bias) to LDS, top-8 + softmax + scatter ----
    __syncthreads();                           // staging LDS dead; alias as float
    float* lg = (float*)hsm;                   // [64 tok][68]
    float* sc = (float*)hsm + 64 * 68;         // [64 tok][65]

    // D layout (verified r8): token row = (l>>4)*4+q, expert col = n*16+(l&15)
    #pragma unroll
    for (int n = 0; n < 4; ++n) {
        float b = bias[n * 16 + (l & 15)];
        #pragma unroll
        for (int q = 0; q < 4; ++q) {
            int trow = w * 16 + (l >> 4) * 4 + q;
            lg[trow * 68 + n * 16 + (l & 15)] = acc[n][q] + b;
        }
    }
    for (int i = tid; i < 64 * 65; i += 256) sc[i] = 0.f;
    __syncthreads();

    if (tid < 64) {
        const int t = tid;
        float v[64];
        #pragma unroll
        for (int e = 0; e < 64; ++e) v[e] = lg[t * 68 + e];

        float tvals[TOPK]; int tix[TOPK]; float probs[TOPK];
        unsigned long long chosen = 0ull;
        #pragma unroll
        for (int j = 0; j < TOPK; ++j) {
            float best = -INFINITY; int bi = 0;
            #pragma unroll
            for (int e = 0; e < 64; ++e) {
                bool ok = ((chosen >> e) & 1ull) == 0ull;
                if (ok && v[e] > best) { best = v[e]; bi = e; }  // strict >: lowest idx on tie
            }
            chosen |= (1ull << bi);
            tvals[j] = best; tix[j] = bi;
        }
        float m = tvals[0];
        float ssum = 0.f;
        #pragma unroll
        for (int j = 0; j < TOPK; ++j) { probs[j] = __expf(tvals[j] - m); ssum += probs[j]; }
        float inv = 1.f / ssum;
        #pragma unroll
        for (int j = 0; j < TOPK; ++j) probs[j] *= inv;

        #pragma unroll
        for (int j = 0; j < TOPK; ++j) sc[t * 65 + tix[j]] = probs[j];

        float* oidx = out + (size_t)TOKENS * EXPERTS;
        const int token = g * 64 + t;
        #pragma unroll
        for (int j = 0; j < TOPK; ++j) oidx[(size_t)token * TOPK + j] = (float)tix[j];
    }
    __syncthreads();

    // ---- coalesced score write: 64 tokens x 64 experts = 1024 float4 ----
    float* oscore = out + (size_t)g * 4096;
    #pragma unroll
    for (int p = 0; p < 4; ++p) {
        int fi  = tid + 256 * p;               // float4 index 0..1023
        int tok = fi >> 4;
        int es  = (fi & 15) * 4;
        float4 vv;
        vv.x = sc[tok * 65 + es + 0];
        vv.y = sc[tok * 65 + es + 1];
        vv.z = sc[tok * 65 + es + 2];
        vv.w = sc[tok * 65 + es + 3];
        *(float4*)(oscore + (size_t)fi * 4) = vv;
    }
}

extern "C" void kernel_launch(void* const* d_in, const int* in_sizes, int n_in,
                              void* d_out, int out_size, void* d_ws, size_t ws_size,
                              hipStream_t stream) {
    const float* A    = (const float*)d_in[0];   // [32768, 2048] fp32
    const float* W    = (const float*)d_in[1];   // [64, 2048] fp32
    const float* bias = (const float*)d_in[2];   // [64] fp32
    float* out = (float*)d_out;                  // scores (32768*64) ++ idx (32768*8)
    (void)d_ws; (void)ws_size;

    router_mfma<<<TOKENS / 64, 256, 0, stream>>>(A, W, bias, out);
}